// Round 10
// baseline (1013.502 us; speedup 1.0000x reference)
//
#include <hip/hip_runtime.h>
#include <hip/hip_bf16.h>
#include <stdint.h>

// Problem constants (fixed by the reference)
#define NN   50000
#define RR   50
#define BB   30
#define DIN  64
#define EE   1000000
#define NREC (EE + NN)        // edges + one self-record per node

// Y table geometry per layer: row = (src-s0), col = rel*DOUT + o
#define NCW0   3264           // 51*64 valid cols (layers 0,1)
#define RLEN0  3264           // row stride (elems)
#define CB0    13             // ceil(3264/256)
#define NCW2   408            // 51*8 valid cols (layer 2)
#define RLEN2  416            // padded row stride
#define CB2    2

typedef __attribute__((ext_vector_type(8))) short short8;
typedef __attribute__((ext_vector_type(4))) float floatx4;

#define RFL(x) __builtin_amdgcn_readfirstlane(x)

__device__ __forceinline__ float bf2f(unsigned short u) {
    return __int_as_float(((int)u) << 16);
}
__device__ __forceinline__ short f2bf(float f) {
    __hip_bfloat16 h = __float2bfloat16(f);
    return *reinterpret_cast<const short*>(&h);
}

// ---------------- preprocessing: counting sort of edges by dst ----------------

__global__ void k_hist(const int* __restrict__ dst, const int* __restrict__ et,
                       int* __restrict__ cnt, int* __restrict__ dcount) {
    int e = blockIdx.x * 256 + threadIdx.x;
    if (e < EE) {
        int d = dst[e], r = et[e];
        atomicAdd(&cnt[d * RR + r], 1);
        atomicAdd(&dcount[d], 1);
    }
}

// exclusive scan over (dcount[i] + 1)  (the +1 is the self/root record)
__global__ void k_scan1(const int* __restrict__ dcount, int* __restrict__ doff,
                        int* __restrict__ bsum) {
    __shared__ int sh[256];
    int t = threadIdx.x;
    int i = blockIdx.x * 256 + t;
    int v = (i < NN) ? (dcount[i] + 1) : 0;
    sh[t] = v;
    __syncthreads();
    for (int s = 1; s < 256; s <<= 1) {
        int add = (t >= s) ? sh[t - s] : 0;
        __syncthreads();
        sh[t] += add;
        __syncthreads();
    }
    int incl = sh[t];
    if (i < NN) doff[i] = incl - v;
    if (t == 255) bsum[blockIdx.x] = incl;
}

__global__ void k_scan2(int* __restrict__ bsum, int nbv) {
    __shared__ int sh[256];
    int t = threadIdx.x;
    int v = (t < nbv) ? bsum[t] : 0;
    sh[t] = v;
    __syncthreads();
    for (int s = 1; s < 256; s <<= 1) {
        int add = (t >= s) ? sh[t - s] : 0;
        __syncthreads();
        sh[t] += add;
        __syncthreads();
    }
    if (t < nbv) bsum[t] = sh[t] - v;
}

// finalize offsets + write the self-record {n, rel=50, alpha=1}
__global__ void k_scan3(int* __restrict__ doff, const int* __restrict__ bsum,
                        int4* __restrict__ rec) {
    int i = blockIdx.x * 256 + threadIdx.x;
    if (i < NN) {
        int o = doff[i] + bsum[blockIdx.x];
        doff[i] = o;
        rec[o] = make_int4(i, RR, 0x3f800000, 0);   // alpha = 1.0f
    }
}

__global__ void k_scatter(const int* __restrict__ src, const int* __restrict__ dst,
                          const int* __restrict__ et, const int* __restrict__ cnt,
                          const int* __restrict__ doff, int* __restrict__ cursor,
                          int4* __restrict__ rec) {
    int e = blockIdx.x * 256 + threadIdx.x;
    if (e < EE) {
        int d = dst[e], r = et[e], s = src[e];
        int p = doff[d] + 1 + atomicAdd(&cursor[d], 1);   // slot 0 = self
        float a = 1.0f / (float)cnt[d * RR + r];
        rec[p] = make_int4(s, r, __float_as_int(a), 0);
    }
}

__global__ void k_cast_x(const float* __restrict__ x, short* __restrict__ h) {
    int i = blockIdx.x * 256 + threadIdx.x;
    if (i < NN * DIN) h[i] = f2bf(x[i]);
}

// Build W-tables for all 3 layers (bf16, transposed): Wt[col][k], col = r*DOUT+o.
// r<50: Wt = sum_b comp[r,b]*bases[b,k,o]; r==50: root[k,o].
// Segment row starts (padded): L0 at 0 (3328 rows), L1 at 3328, L2 at 6656 (512 rows).
__global__ void k_wcat(const float* __restrict__ b0, const float* __restrict__ c0, const float* __restrict__ r0,
                       const float* __restrict__ b1, const float* __restrict__ c1, const float* __restrict__ r1,
                       const float* __restrict__ b2, const float* __restrict__ c2, const float* __restrict__ r2,
                       short* __restrict__ wt) {
    int idx = blockIdx.x * 256 + threadIdx.x;   // (globalrow, k)
    if (idx >= (NCW0 + NCW0 + NCW2) * DIN) return;
    int gr = idx >> 6, k = idx & 63;
    const float *bs, *cp, *rt; int row, dout; size_t segbase;
    if (gr < NCW0)            { bs = b0; cp = c0; rt = r0; row = gr;             dout = 64; segbase = 0; }
    else if (gr < 2 * NCW0)   { bs = b1; cp = c1; rt = r1; row = gr - NCW0;      dout = 64; segbase = (size_t)3328 * 64; }
    else                      { bs = b2; cp = c2; rt = r2; row = gr - 2 * NCW0;  dout = 8;  segbase = (size_t)6656 * 64; }
    int r = row / dout, o = row - r * dout;
    float v;
    if (r < RR) {
        v = 0.f;
        for (int b = 0; b < BB; ++b)
            v = fmaf(cp[r * BB + b], bs[(b * 64 + k) * dout + o], v);
    } else {
        v = rt[k * dout + o];
    }
    wt[segbase + (size_t)row * 64 + k] = f2bf(v);
}

// ---------------- Y GEMM: Y[s-s0][col] = sum_k h[s][k] * Wt[col][k] ----------------
// block 256 = 4 waves; tile = 16 nodes x 256 cols; K=64 (2 MFMA steps).
__global__ __launch_bounds__(256, 8)
void k_gemm(const short* __restrict__ h, const short* __restrict__ wt,
            short* __restrict__ Y, int s0, int ncw, int rowlen) {
    __shared__ __align__(16) short a_tile[16 * 72];   // +8 pad breaks bank aliasing
    __shared__ __align__(16) short o_tile[16 * 256];
    const int tid  = threadIdx.x;
    const int lane = tid & 63;
    const int wv   = tid >> 6;
    const int mm   = lane & 15;
    const int qq   = lane >> 4;
    const int bx   = blockIdx.x;
    const int cb   = blockIdx.y;

    {   // stage A: 16 rows x 64 cols bf16
        const int row = tid >> 4, col = (tid & 15) * 4;
        *(int2*)&a_tile[row * 72 + col] =
            *(const int2*)(h + ((size_t)(s0 + bx * 16)) * 64 + tid * 4);
    }
    __syncthreads();

    const short* arow = a_tile + mm * 72 + qq * 8;
    short8 a0 = *(const short8*)arow;
    short8 a1 = *(const short8*)(arow + 32);
#pragma unroll
    for (int ct = 0; ct < 4; ++ct) {
        const int colb = cb * 256 + wv * 64 + ct * 16;
        const short* wrow = wt + (size_t)(colb + mm) * 64 + qq * 8;
        floatx4 p = {0.f, 0.f, 0.f, 0.f};
        p = __builtin_amdgcn_mfma_f32_16x16x32_bf16(a0, *(const short8*)wrow, p, 0, 0, 0);
        p = __builtin_amdgcn_mfma_f32_16x16x32_bf16(a1, *(const short8*)(wrow + 32), p, 0, 0, 0);
#pragma unroll
        for (int r = 0; r < 4; ++r)
            o_tile[(qq * 4 + r) * 256 + wv * 64 + ct * 16 + mm] = f2bf(p[r]);
    }
    __syncthreads();

    {   // coalesced copy out: thread -> 32B of one row
        const int row = tid >> 4, c16 = tid & 15;
        const int c0 = cb * 256 + c16 * 16;
        if (c0 < ncw) {
            const int4* sp = (const int4*)&o_tile[row * 256 + c16 * 16];
            int4 v0 = sp[0], v1 = sp[1];
            int4* dp = (int4*)(Y + (size_t)(bx * 16 + row) * rowlen + c0);
            dp[0] = v0; dp[1] = v1;
        }
    }
}

// ---------------- aggregation: msg[n] = bias + sum_e alpha*Y[src,rel,:] ----------------
// block 256 = 4 waves, one node/wave, lane = output feature.
__global__ __launch_bounds__(256, 8)
void k_agg64(const short* __restrict__ Y, const int4* __restrict__ rec,
             const int* __restrict__ doff, const int* __restrict__ dcount,
             const float* __restrict__ bias, float* __restrict__ macc,
             short* __restrict__ hnext,
             int s0, int s1, int first, int last) {
    const int tid  = threadIdx.x;
    const int lane = tid & 63;
    const int n    = blockIdx.x * 4 + (tid >> 6);
    float acc = first ? bias[lane] : macc[(size_t)n * 64 + lane];
    const int beg = RFL(doff[n]);
    const int ce  = RFL(dcount[n]) + 1;
#pragma unroll 4
    for (int e = 0; e < ce; ++e) {
        int4 rc = rec[beg + e];
        const int s = RFL(rc.x);
        if (s >= s0 && s < s1) {
            const int   r = RFL(rc.y);
            const float a = __int_as_float(RFL(rc.z));
            unsigned short yv = ((const unsigned short*)Y)
                [(size_t)(s - s0) * RLEN0 + r * 64 + lane];
            acc = fmaf(a, bf2f(yv), acc);
        }
    }
    if (last) hnext[(size_t)n * 64 + lane] = f2bf(fmaxf(acc, 0.f));
    else      macc[(size_t)n * 64 + lane] = acc;
}

// layer-3 aggregation + log_softmax (dout=8); lanes replicate per octet.
__global__ __launch_bounds__(256, 8)
void k_agg8(const short* __restrict__ Y, const int4* __restrict__ rec,
            const int* __restrict__ doff, const int* __restrict__ dcount,
            const float* __restrict__ bias, float* __restrict__ macc,
            float* __restrict__ outp,
            int s0, int s1, int first, int last) {
    const int tid  = threadIdx.x;
    const int lane = tid & 63;
    const int o    = lane & 7;
    const int n    = blockIdx.x * 4 + (tid >> 6);
    float acc = first ? bias[o] : macc[(size_t)n * 8 + o];
    const int beg = RFL(doff[n]);
    const int ce  = RFL(dcount[n]) + 1;
#pragma unroll 4
    for (int e = 0; e < ce; ++e) {
        int4 rc = rec[beg + e];
        const int s = RFL(rc.x);
        if (s >= s0 && s < s1) {
            const int   r = RFL(rc.y);
            const float a = __int_as_float(RFL(rc.z));
            unsigned short yv = ((const unsigned short*)Y)
                [(size_t)(s - s0) * RLEN2 + r * 8 + o];
            acc = fmaf(a, bf2f(yv), acc);
        }
    }
    if (last) {
        float m = acc;
        m = fmaxf(m, __shfl_xor(m, 1, 8));
        m = fmaxf(m, __shfl_xor(m, 2, 8));
        m = fmaxf(m, __shfl_xor(m, 4, 8));
        float ex = expf(acc - m);
        float sm = ex;
        sm += __shfl_xor(sm, 1, 8);
        sm += __shfl_xor(sm, 2, 8);
        sm += __shfl_xor(sm, 4, 8);
        float ls = logf(sm);
        if (lane < 8) outp[(size_t)n * 8 + lane] = acc - m - ls;
    } else if (lane < 8) {
        macc[(size_t)n * 8 + o] = acc;
    }
}

// ---------------- launch ----------------
extern "C" void kernel_launch(void* const* d_in, const int* in_sizes, int n_in,
                              void* d_out, int out_size, void* d_ws, size_t ws_size,
                              hipStream_t stream) {
    const float* x     = (const float*)d_in[0];
    const int*   eidx  = (const int*)d_in[1];
    const int*   etype = (const int*)d_in[2];
    const float* bases0 = (const float*)d_in[3];
    const float* comp0  = (const float*)d_in[4];
    const float* root0  = (const float*)d_in[5];
    const float* bias0  = (const float*)d_in[6];
    const float* bases1 = (const float*)d_in[7];
    const float* comp1  = (const float*)d_in[8];
    const float* root1  = (const float*)d_in[9];
    const float* bias1  = (const float*)d_in[10];
    const float* bases2 = (const float*)d_in[11];
    const float* comp2  = (const float*)d_in[12];
    const float* root2  = (const float*)d_in[13];
    const float* bias2  = (const float*)d_in[14];
    const int* srcp = eidx;
    const int* dstp = eidx + EE;

    char* p = (char*)d_ws;
    auto carve = [&](size_t bytes) -> char* {
        char* r = p;
        p += (bytes + 255) & ~(size_t)255;
        return r;
    };
    int*  cnt    = (int*)carve((size_t)NN * RR * sizeof(int));   // 10 MB
    int*  dcount = (int*)carve((size_t)NN * sizeof(int));
    int*  cursor = (int*)carve((size_t)NN * sizeof(int));
    int*  doff   = (int*)carve((size_t)NN * sizeof(int));
    int*  bsum   = (int*)carve(256 * sizeof(int));
    int4* rec    = (int4*)carve((size_t)NREC * sizeof(int4));    // 16.8 MB
    short* h0    = (short*)carve((size_t)NN * DIN * 2);
    short* h1    = (short*)carve((size_t)NN * DIN * 2);
    short* h2    = (short*)carve((size_t)NN * DIN * 2);
    float* macc  = (float*)carve((size_t)NN * DIN * sizeof(float)); // 12.8 MB (chunked path)
    short* wtA   = (short*)carve((size_t)(3328 + 3328 + 512) * 64 * sizeof(short)); // 917 KB
    short* Ybuf  = (short*)p;   // remainder of workspace

    // dynamic chunking by available Y space (graceful if ws is small)
    size_t fixed  = (size_t)((char*)Ybuf - (char*)d_ws);
    size_t budget = (ws_size > fixed + (1u << 20)) ? (ws_size - fixed - (1u << 20)) : 0;
    long per_node = (long)RLEN0 * 2;   // 6528 B/node (layer-0/1 rows dominate)
    long cn = (long)(budget / per_node);
    int chunk_nodes = (cn >= NN) ? NN : (int)(cn & ~15L);
    if (chunk_nodes < 16) chunk_nodes = 16;
    const int nch = (NN + chunk_nodes - 1) / chunk_nodes;

    hipMemsetAsync(cnt, 0, (size_t)NN * (RR + 2) * sizeof(int) + 512, stream);

    const int EB = (EE + 255) / 256;   // 3907
    const int NB = (NN + 255) / 256;   // 196
    k_hist<<<EB, 256, 0, stream>>>(dstp, etype, cnt, dcount);
    k_scan1<<<NB, 256, 0, stream>>>(dcount, doff, bsum);
    k_scan2<<<1, 256, 0, stream>>>(bsum, NB);
    k_scan3<<<NB, 256, 0, stream>>>(doff, bsum, rec);
    k_scatter<<<EB, 256, 0, stream>>>(srcp, dstp, etype, cnt, doff, cursor, rec);
    k_cast_x<<<(NN * DIN + 255) / 256, 256, 0, stream>>>(x, h0);
    k_wcat<<<((NCW0 + NCW0 + NCW2) * DIN + 255) / 256, 256, 0, stream>>>(
        bases0, comp0, root0, bases1, comp1, root1, bases2, comp2, root2, wtA);

    const short* wseg[3] = { wtA, wtA + (size_t)3328 * 64, wtA + (size_t)6656 * 64 };
    const short* hin[3]  = { h0, h1, h2 };
    short*       hout[2] = { h1, h2 };
    const float* bia[3]  = { bias0, bias1, bias2 };

    for (int l = 0; l < 3; ++l) {
        const int ncw    = (l < 2) ? NCW0 : NCW2;
        const int rowlen = (l < 2) ? RLEN0 : RLEN2;
        const int cbs    = (l < 2) ? CB0 : CB2;
        for (int c = 0; c < nch; ++c) {
            const int s0 = c * chunk_nodes;
            const int s1 = (s0 + chunk_nodes < NN) ? s0 + chunk_nodes : NN;
            const int tiles = (s1 - s0) / 16;
            k_gemm<<<dim3(tiles, cbs), 256, 0, stream>>>(hin[l], wseg[l], Ybuf, s0, ncw, rowlen);
            const int first = (c == 0), lastc = (c == nch - 1);
            if (l < 2)
                k_agg64<<<NN / 4, 256, 0, stream>>>(Ybuf, rec, doff, dcount, bia[l],
                                                    macc, hout[l], s0, s1, first, lastc);
            else
                k_agg8<<<NN / 4, 256, 0, stream>>>(Ybuf, rec, doff, dcount, bia[l],
                                                   macc, (float*)d_out, s0, s1, first, lastc);
        }
    }
}